// Round 12
// baseline (378.666 us; speedup 1.0000x reference)
//
#include <hip/hip_runtime.h>

#define B_    64
#define C_    9
#define T_    8192
#define PCD_  16
#define E_    128
#define K_    7
#define CP_   144     // C_*PCD_  (GEMM K)
#define KPAD  160     // padded GEMM K (multiple of 32)
#define TTILE 64
#define NTILE 8       // t-tiles per block -> grid 64*16=1024, all-resident
#define YSTR  168     // y row stride (bf16): 336B -> 2-way bank alias only (free)
#define EPS_  1e-5f

typedef __bf16 bf16x8 __attribute__((ext_vector_type(8)));
typedef float  f32x4  __attribute__((ext_vector_type(4)));

// prepass: w_proj [128][144] f32 -> bf16 [128][160], zero-padded cols 144..159
__global__ void prep_wb_kernel(const float* __restrict__ w_proj, __bf16* __restrict__ wb) {
    int idx = blockIdx.x * 256 + threadIdx.x;      // 0..20479
    int row = idx / KPAD;
    int col = idx - row * KPAD;
    float v = (col < CP_) ? w_proj[row * CP_ + col] : 0.f;
    wb[idx] = (__bf16)v;
}

__global__ __launch_bounds__(256)
void fused_kernel(const float* __restrict__ x, const float* __restrict__ w_conv,
                  const float* __restrict__ b_conv, const __bf16* __restrict__ wb,
                  const float* __restrict__ b_proj, const float* __restrict__ gamma,
                  const float* __restrict__ beta, float* __restrict__ out) {
    __shared__ __align__(16) float  xbuf[2][C_ * 72];      // 5184 B double-buffered x
    __shared__ __align__(16) __bf16 y_lds[TTILE * YSTR];   // 21504 B
    __shared__ __align__(16) float  cba[3 * E_];           // b_proj|gamma|beta 1536 B

    const int tid  = threadIdx.x;
    const int bb   = blockIdx.x >> 4;        // batch (64)
    const int grp  = blockIdx.x & 15;        // t-group (16), 512 t's per block
    const int tbase = grp << 9;

    const int lane = tid & 63;
    const int wid  = tid >> 6;
    const int n0 = wid * 16, fr = lane & 15, kg = lane >> 4;

    // ---- A operand (w_proj bf16) -> REGISTERS, once per block (tile-invariant).
    // 40 x b128 = 160 VGPR/lane. Kills the per-tile L2 load chain that was the
    // critical path at VGPR_Count=48 (no hoisting room).
    bf16x8 areg[5][8];
    #pragma unroll
    for (int ks = 0; ks < 5; ++ks)
        #pragma unroll
        for (int et = 0; et < 8; ++et)
            areg[ks][et] = *(const bf16x8*)&wb[(et * 16 + fr) * KPAD + ks * 32 + kg * 8];

    // conv weights -> registers (lanes 0..143)
    float wreg[K_];
    float bias = 0.f;
    if (tid < CP_) {
        #pragma unroll
        for (int k = 0; k < K_; ++k) wreg[k] = w_conv[tid * K_ + k];
        bias = b_conv[tid];
    }

    // epilogue constants -> LDS (broadcast reads later, no per-tile L2 latency)
    for (int o = tid; o < 3 * E_; o += 256) {
        float v = (o < E_) ? b_proj[o] : (o < 2 * E_ ? gamma[o - E_] : beta[o - 2 * E_]);
        cba[o] = v;
    }

    const float* xb = x + (size_t)bb * (C_ * T_);
    // prologue: stage x tile 0 (all threads)
    for (int o = tid; o < C_ * 70; o += 256) {
        int c = o / 70, i = o - c * 70, gt = tbase - 3 + i;
        xbuf[0][c * 72 + i] = (gt >= 0 && gt < T_) ? xb[c * T_ + gt] : 0.f;
    }
    // zero y K-pad cols 144..159 once (conv never writes them)
    for (int o = tid; o < TTILE * 8; o += 256) {
        int row = o >> 3, d = o & 7;
        *(unsigned int*)&y_lds[row * YSTR + CP_ + d * 2] = 0u;
    }
    __syncthreads();

    for (int tile = 0; tile < NTILE; ++tile) {
        const int t0  = tbase + (tile << 6);
        const int cur = tile & 1;

        // ---- phase 1: conv (waves 0-2) || prefetch next x tile (wave 3) ----
        if (tid < CP_) {
            const int c = tid >> 4;
            const float* xr = &xbuf[cur][c * 72];
            #pragma unroll
            for (int tc = 0; tc < TTILE; tc += 8) {
                float xa[14];
                #pragma unroll
                for (int i = 0; i < 14; ++i) xa[i] = xr[tc + i];
                #pragma unroll
                for (int j = 0; j < 8; ++j) {
                    float acc = bias;
                    #pragma unroll
                    for (int k = 0; k < K_; ++k) acc += xa[j + k] * wreg[k];
                    y_lds[(tc + j) * YSTR + tid] = (__bf16)fmaxf(acc, 0.f);
                }
            }
        } else if (tid >= 192 && tile < NTILE - 1) {
            // wave 3 stages x(tile+1) into the other buffer; disjoint from conv reads
            const int t0n = t0 + TTILE;
            const int so  = tid - 192;       // 0..63
            float v[10];
            #pragma unroll
            for (int j = 0; j < 10; ++j) {
                int o = so + j * 64;
                v[j] = 0.f;
                if (o < C_ * 70) {
                    int c = o / 70, i = o - c * 70, gt = t0n - 3 + i;
                    if (gt >= 0 && gt < T_) v[j] = xb[c * T_ + gt];
                }
            }
            #pragma unroll
            for (int j = 0; j < 10; ++j) {
                int o = so + j * 64;
                if (o < C_ * 70) {
                    int c = o / 70, i = o - c * 70;
                    xbuf[cur ^ 1][c * 72 + i] = v[j];
                }
            }
        }
        __syncthreads();   // y ready, next-x staged

        // ---- phase 2: MFMA  D[m=e][n=t]; A = areg (registers), B = y (LDS) ----
        f32x4 acc[8];
        #pragma unroll
        for (int e = 0; e < 8; ++e) acc[e] = (f32x4){0.f, 0.f, 0.f, 0.f};

        #pragma unroll
        for (int ks = 0; ks < 5; ++ks) {
            const int k0 = ks * 32 + kg * 8;
            bf16x8 bfrag = *(const bf16x8*)&y_lds[(n0 + fr) * YSTR + k0];
            #pragma unroll
            for (int et = 0; et < 8; ++et) {
                acc[et] = __builtin_amdgcn_mfma_f32_16x16x32_bf16(areg[ks][et], bfrag, acc[et], 0, 0, 0);
            }
        }

        // ---- epilogue: +b_proj, LayerNorm over e, store fp32 ----
        const int t_local = n0 + fr;
        const int g = kg;                    // e = et*16 + g*4 + r
        float s = 0.f, ss = 0.f;
        #pragma unroll
        for (int et = 0; et < 8; ++et) {
            f32x4 bp = *(const f32x4*)&cba[et * 16 + g * 4];
            #pragma unroll
            for (int r = 0; r < 4; ++r) {
                float z = acc[et][r] + bp[r];
                acc[et][r] = z;
                s += z; ss += z * z;
            }
        }
        s  += __shfl_xor(s, 16);  s  += __shfl_xor(s, 32);
        ss += __shfl_xor(ss, 16); ss += __shfl_xor(ss, 32);
        const float mean = s * (1.f / 128.f);
        const float var  = ss * (1.f / 128.f) - mean * mean;
        const float rstd = rsqrtf(var + EPS_);

        float* orow = out + ((size_t)(bb * T_ + t0 + t_local)) * E_;
        #pragma unroll
        for (int et = 0; et < 8; ++et) {
            f32x4 gm = *(const f32x4*)&cba[E_ + et * 16 + g * 4];
            f32x4 bt = *(const f32x4*)&cba[2 * E_ + et * 16 + g * 4];
            f32x4 o4;
            #pragma unroll
            for (int r = 0; r < 4; ++r)
                o4[r] = (acc[et][r] - mean) * rstd * gm[r] + bt[r];
            *(f32x4*)&orow[et * 16 + g * 4] = o4;
        }

        if (tile < NTILE - 1) __syncthreads();   // y free + xbuf[next] visible
    }
}

extern "C" void kernel_launch(void* const* d_in, const int* in_sizes, int n_in,
                              void* d_out, int out_size, void* d_ws, size_t ws_size,
                              hipStream_t stream) {
    const float* x      = (const float*)d_in[0];
    const float* w_conv = (const float*)d_in[1];
    const float* b_conv = (const float*)d_in[2];
    const float* w_proj = (const float*)d_in[3];
    const float* b_proj = (const float*)d_in[4];
    const float* gamma  = (const float*)d_in[5];
    const float* beta   = (const float*)d_in[6];
    float* out = (float*)d_out;
    __bf16* wb = (__bf16*)d_ws;   // 128*160*2 = 40960 B

    hipLaunchKernelGGL(prep_wb_kernel, dim3(80), dim3(256), 0, stream, w_proj, wb);
    hipLaunchKernelGGL(fused_kernel, dim3(B_ * 16), dim3(256), 0, stream,
                       x, w_conv, b_conv, wb, b_proj, gamma, beta, out);
}

// Round 13
// 377.722 us; speedup vs baseline: 1.0025x; 1.0025x over previous
//
#include <hip/hip_runtime.h>

#define B_    64
#define C_    9
#define T_    8192
#define PCD_  16
#define E_    128
#define K_    7
#define CP_   144     // C_*PCD_  (GEMM K)
#define KPAD  160     // padded GEMM K (multiple of 32)
#define TTILE 64
#define NTILE 8       // t-tiles per block -> grid 64*16=1024, all-resident
#define YSTR  168     // y row stride (bf16): 336B -> 2-way bank alias only (free)
#define EPS_  1e-5f

// Barrier that waits only on LDS ops (lgkmcnt), NOT on outstanding global
// stores/loads (vmcnt). __syncthreads would drain vmcnt(0) every tile --
// that store-drain is the structural stall. All cross-wave deps here are
// LDS (y_lds, xbuf); stores to `out` are never read; wave-3 prefetch's
// vmcnt is enforced intra-wave by its reg->ds_write data dependency.
#define BAR_LGKM() asm volatile("s_waitcnt lgkmcnt(0)\n\ts_barrier" ::: "memory")

typedef __bf16 bf16x8 __attribute__((ext_vector_type(8)));
typedef float  f32x4  __attribute__((ext_vector_type(4)));

// prepass: w_proj [128][144] f32 -> bf16 [128][160], zero-padded cols 144..159
__global__ void prep_wb_kernel(const float* __restrict__ w_proj, __bf16* __restrict__ wb) {
    int idx = blockIdx.x * 256 + threadIdx.x;      // 0..20479
    int row = idx / KPAD;
    int col = idx - row * KPAD;
    float v = (col < CP_) ? w_proj[row * CP_ + col] : 0.f;
    wb[idx] = (__bf16)v;
}

__global__ __launch_bounds__(256)
void fused_kernel(const float* __restrict__ x, const float* __restrict__ w_conv,
                  const float* __restrict__ b_conv, const __bf16* __restrict__ wb,
                  const float* __restrict__ b_proj, const float* __restrict__ gamma,
                  const float* __restrict__ beta, float* __restrict__ out) {
    __shared__ __align__(16) float  xbuf[2][C_ * 72];      // 5184 B double-buffered x
    __shared__ __align__(16) __bf16 y_lds[TTILE * YSTR];   // 21504 B
    __shared__ __align__(16) float  cba[3 * E_];           // b_proj|gamma|beta 1536 B

    const int tid  = threadIdx.x;
    const int bb   = blockIdx.x >> 4;        // batch (64)
    const int grp  = blockIdx.x & 15;        // t-group (16), 512 t's per block
    const int tbase = grp << 9;

    const int lane = tid & 63;
    const int wid  = tid >> 6;
    const int n0 = wid * 16, fr = lane & 15, kg = lane >> 4;

    // A operand (w_proj bf16) -> registers once per block (tile-invariant).
    bf16x8 areg[5][8];
    #pragma unroll
    for (int ks = 0; ks < 5; ++ks)
        #pragma unroll
        for (int et = 0; et < 8; ++et)
            areg[ks][et] = *(const bf16x8*)&wb[(et * 16 + fr) * KPAD + ks * 32 + kg * 8];

    // conv weights -> registers (lanes 0..143)
    float wreg[K_];
    float bias = 0.f;
    if (tid < CP_) {
        #pragma unroll
        for (int k = 0; k < K_; ++k) wreg[k] = w_conv[tid * K_ + k];
        bias = b_conv[tid];
    }

    // epilogue constants -> LDS
    for (int o = tid; o < 3 * E_; o += 256) {
        float v = (o < E_) ? b_proj[o] : (o < 2 * E_ ? gamma[o - E_] : beta[o - 2 * E_]);
        cba[o] = v;
    }

    const float* xb = x + (size_t)bb * (C_ * T_);
    // prologue: stage x tile 0 (all threads)
    for (int o = tid; o < C_ * 70; o += 256) {
        int c = o / 70, i = o - c * 70, gt = tbase - 3 + i;
        xbuf[0][c * 72 + i] = (gt >= 0 && gt < T_) ? xb[c * T_ + gt] : 0.f;
    }
    // zero y K-pad cols 144..159 once
    for (int o = tid; o < TTILE * 8; o += 256) {
        int row = o >> 3, d = o & 7;
        *(unsigned int*)&y_lds[row * YSTR + CP_ + d * 2] = 0u;
    }
    __syncthreads();   // once per block: full barrier is fine here

    for (int tile = 0; tile < NTILE; ++tile) {
        const int t0  = tbase + (tile << 6);
        const int cur = tile & 1;

        // ---- phase 1: conv (waves 0-2) || prefetch next x tile (wave 3) ----
        if (tid < CP_) {
            const int c = tid >> 4;
            const float* xr = &xbuf[cur][c * 72];
            #pragma unroll
            for (int tc = 0; tc < TTILE; tc += 8) {
                float xa[14];
                #pragma unroll
                for (int i = 0; i < 14; ++i) xa[i] = xr[tc + i];
                #pragma unroll
                for (int j = 0; j < 8; ++j) {
                    float acc = bias;
                    #pragma unroll
                    for (int k = 0; k < K_; ++k) acc += xa[j + k] * wreg[k];
                    y_lds[(tc + j) * YSTR + tid] = (__bf16)fmaxf(acc, 0.f);
                }
            }
        } else if (tid >= 192 && tile < NTILE - 1) {
            const int t0n = t0 + TTILE;
            const int so  = tid - 192;       // 0..63
            float v[10];
            #pragma unroll
            for (int j = 0; j < 10; ++j) {
                int o = so + j * 64;
                v[j] = 0.f;
                if (o < C_ * 70) {
                    int c = o / 70, i = o - c * 70, gt = t0n - 3 + i;
                    if (gt >= 0 && gt < T_) v[j] = xb[c * T_ + gt];
                }
            }
            #pragma unroll
            for (int j = 0; j < 10; ++j) {
                int o = so + j * 64;
                if (o < C_ * 70) {
                    int c = o / 70, i = o - c * 70;
                    xbuf[cur ^ 1][c * 72 + i] = v[j];
                }
            }
        }
        BAR_LGKM();   // y ready, next-x staged; stores keep flying

        // ---- phase 2: MFMA  D[m=e][n=t]; A = areg, B = y (LDS) ----
        f32x4 acc[8];
        #pragma unroll
        for (int e = 0; e < 8; ++e) acc[e] = (f32x4){0.f, 0.f, 0.f, 0.f};

        #pragma unroll
        for (int ks = 0; ks < 5; ++ks) {
            const int k0 = ks * 32 + kg * 8;
            bf16x8 bfrag = *(const bf16x8*)&y_lds[(n0 + fr) * YSTR + k0];
            #pragma unroll
            for (int et = 0; et < 8; ++et) {
                acc[et] = __builtin_amdgcn_mfma_f32_16x16x32_bf16(areg[ks][et], bfrag, acc[et], 0, 0, 0);
            }
        }

        // ---- epilogue: +b_proj, LayerNorm over e, store fp32 ----
        const int t_local = n0 + fr;
        const int g = kg;                    // e = et*16 + g*4 + r
        float s = 0.f, ss = 0.f;
        #pragma unroll
        for (int et = 0; et < 8; ++et) {
            f32x4 bp = *(const f32x4*)&cba[et * 16 + g * 4];
            #pragma unroll
            for (int r = 0; r < 4; ++r) {
                float z = acc[et][r] + bp[r];
                acc[et][r] = z;
                s += z; ss += z * z;
            }
        }
        s  += __shfl_xor(s, 16);  s  += __shfl_xor(s, 32);
        ss += __shfl_xor(ss, 16); ss += __shfl_xor(ss, 32);
        const float mean = s * (1.f / 128.f);
        const float var  = ss * (1.f / 128.f) - mean * mean;
        const float rstd = rsqrtf(var + EPS_);

        float* orow = out + ((size_t)(bb * T_ + t0 + t_local)) * E_;
        #pragma unroll
        for (int et = 0; et < 8; ++et) {
            f32x4 gm = *(const f32x4*)&cba[E_ + et * 16 + g * 4];
            f32x4 bt = *(const f32x4*)&cba[2 * E_ + et * 16 + g * 4];
            f32x4 o4;
            #pragma unroll
            for (int r = 0; r < 4; ++r)
                o4[r] = (acc[et][r] - mean) * rstd * gm[r] + bt[r];
            *(f32x4*)&orow[et * 16 + g * 4] = o4;
        }

        if (tile < NTILE - 1) BAR_LGKM();   // y free + xbuf[next] visible; no vmcnt drain
    }
}

extern "C" void kernel_launch(void* const* d_in, const int* in_sizes, int n_in,
                              void* d_out, int out_size, void* d_ws, size_t ws_size,
                              hipStream_t stream) {
    const float* x      = (const float*)d_in[0];
    const float* w_conv = (const float*)d_in[1];
    const float* b_conv = (const float*)d_in[2];
    const float* w_proj = (const float*)d_in[3];
    const float* b_proj = (const float*)d_in[4];
    const float* gamma  = (const float*)d_in[5];
    const float* beta   = (const float*)d_in[6];
    float* out = (float*)d_out;
    __bf16* wb = (__bf16*)d_ws;   // 128*160*2 = 40960 B

    hipLaunchKernelGGL(prep_wb_kernel, dim3(80), dim3(256), 0, stream, w_proj, wb);
    hipLaunchKernelGGL(fused_kernel, dim3(B_ * 16), dim3(256), 0, stream,
                       x, w_conv, b_conv, wb, b_proj, gamma, beta, out);
}